// Round 2
// baseline (231.303 us; speedup 1.0000x reference)
//
#include <hip/hip_runtime.h>
#include <hip/hip_bf16.h>
#include <stdint.h>

#define S_SEQ 128
#define N_RES 256
#define CMDIM 256

typedef __attribute__((ext_vector_type(8))) short bf16x8;
typedef __attribute__((ext_vector_type(4))) float f32x4;
typedef __attribute__((ext_vector_type(2))) unsigned int u32x2;

__device__ __forceinline__ unsigned short f32_to_bf16(float f) {
    union { float f; unsigned int u; } v; v.f = f;
    unsigned int u = v.u;
    return (unsigned short)((u + 0x7FFFu + ((u >> 16) & 1u)) >> 16);
}

// ---------------- K0: convert weights to bf16 ----------------
// Wbf[64][256]: rows 0-31 = w1, rows 32-63 = w2. wobf[128][1024].
__global__ __launch_bounds__(256) void k_prep(
    const float* __restrict__ w1, const float* __restrict__ w2,
    const float* __restrict__ wo,
    unsigned short* __restrict__ Wbf, unsigned short* __restrict__ wobf)
{
    int t = blockIdx.x * 256 + threadIdx.x;
    if (t < 16384) {
        float v = (t < 8192) ? w1[t] : w2[t - 8192];
        Wbf[t] = f32_to_bf16(v);
    }
    if (t < 131072) wobf[t] = f32_to_bf16(wo[t]);
}

// ---------------- K1: LayerNorm + dual projection ----------------
// One WG per i (256 WGs). Stores A2[(i*32+c)*128+s], B2[(i*32+d)*128+s].
__global__ __launch_bounds__(256) void k_ln_proj(
    const float* __restrict__ m, const float* __restrict__ lnw, const float* __restrict__ lnb,
    const float* __restrict__ b1, const float* __restrict__ b2,
    const unsigned short* __restrict__ Wbf,
    unsigned short* __restrict__ A2, unsigned short* __restrict__ B2)
{
    __shared__ unsigned short mn[128 * 256];   // 64 KB, rows of 512 B, 16B-chunk XOR swizzle
    int i = blockIdx.x;
    int tid = threadIdx.x;
    int wv = tid >> 6, lane = tid & 63;
    int quad = lane >> 4, l15 = lane & 15;

    f32x4 lw = *(const f32x4*)(lnw + lane * 4);
    f32x4 lb = *(const f32x4*)(lnb + lane * 4);

    for (int r = 0; r < 32; ++r) {
        int s = wv * 32 + r;
        const float* row = m + ((size_t)s * N_RES + i) * CMDIM;
        f32x4 x = *(const f32x4*)(row + lane * 4);
        float s1 = x[0] + x[1] + x[2] + x[3];
        float s2 = x[0]*x[0] + x[1]*x[1] + x[2]*x[2] + x[3]*x[3];
        #pragma unroll
        for (int off = 32; off; off >>= 1) {
            s1 += __shfl_xor(s1, off);
            s2 += __shfl_xor(s2, off);
        }
        float mu = s1 * (1.0f / 256.0f);
        float var = s2 * (1.0f / 256.0f) - mu * mu;
        float rstd = rsqrtf(var + 1e-5f);
        float n0 = (x[0] - mu) * rstd * lw[0] + lb[0];
        float n1 = (x[1] - mu) * rstd * lw[1] + lb[1];
        float n2 = (x[2] - mu) * rstd * lw[2] + lb[2];
        float n3 = (x[3] - mu) * rstd * lw[3] + lb[3];
        unsigned int p0 = (unsigned)f32_to_bf16(n0) | ((unsigned)f32_to_bf16(n1) << 16);
        unsigned int p1 = (unsigned)f32_to_bf16(n2) | ((unsigned)f32_to_bf16(n3) << 16);
        int chunk = lane >> 1;                       // 16B chunk index 0..31
        int pos = (chunk & 16) | ((chunk ^ s) & 15); // XOR swizzle low 4 bits
        unsigned int* dst = (unsigned int*)((char*)mn + s * 512 + pos * 16 + (lane & 1) * 8);
        dst[0] = p0; dst[1] = p1;
    }
    __syncthreads();

    f32x4 acc[4][2];
    #pragma unroll
    for (int a = 0; a < 4; ++a)
        #pragma unroll
        for (int b = 0; b < 2; ++b) acc[a][b] = (f32x4){0.f, 0.f, 0.f, 0.f};

    #pragma unroll
    for (int ks = 0; ks < 8; ++ks) {
        bf16x8 af[4], bfr[2];
        #pragma unroll
        for (int mb = 0; mb < 4; ++mb) {
            int ch = mb * 16 + l15;
            af[mb] = *(const bf16x8*)(Wbf + ch * 256 + ks * 32 + quad * 8);
        }
        #pragma unroll
        for (int nb = 0; nb < 2; ++nb) {
            int srow = wv * 32 + nb * 16 + l15;
            int q = ks * 4 + quad;
            int pos = (q & 16) | ((q ^ srow) & 15);
            bfr[nb] = *(const bf16x8*)((char*)mn + srow * 512 + pos * 16);
        }
        #pragma unroll
        for (int mb = 0; mb < 4; ++mb)
            #pragma unroll
            for (int nb = 0; nb < 2; ++nb)
                acc[mb][nb] = __builtin_amdgcn_mfma_f32_16x16x32_bf16(af[mb], bfr[nb], acc[mb][nb], 0, 0, 0);
    }

    #pragma unroll
    for (int mb = 0; mb < 4; ++mb) {
        const float* bsrc = (mb < 2) ? b1 : b2;
        f32x4 bias = *(const f32x4*)(bsrc + (mb & 1) * 16 + quad * 4);
        unsigned short* dst = (mb < 2) ? A2 : B2;
        #pragma unroll
        for (int nb = 0; nb < 2; ++nb) {
            int s = wv * 32 + nb * 16 + l15;
            #pragma unroll
            for (int reg = 0; reg < 4; ++reg) {
                int ch = (mb & 1) * 16 + quad * 4 + reg;
                float v = acc[mb][nb][reg] + bias[reg];
                dst[((size_t)(i * 32 + ch)) * 128 + s] = f32_to_bf16(v);
            }
        }
    }
}

// ---------------- K2: fused GEMM1+GEMM2 ----------------
// WG = 4 i's x 8 j's = 32 pairs. Stage A: o[pair][cd] (bf16) into swizzled
// LDS via two 128x128 MFMA passes (frags direct from L2-hot A2/B2).
// Stage B: z[zo][pair] = wo . o^T, K=1024, wo frags direct from L2.
// LDS swizzle (both sides): phys_chunk = chunk ^ ((chunk>>3)&7) ^ (pair&7).
__global__ __launch_bounds__(256, 2) void k_fused(
    const unsigned short* __restrict__ A2, const unsigned short* __restrict__ B2,
    const unsigned short* __restrict__ wobf, const float* __restrict__ bo,
    float* __restrict__ out)
{
    __shared__ char olds[32 * 2048];   // 64 KB: 32 pairs x 1024 bf16
    int bx = blockIdx.x;               // i-tile (4 i's)
    int by = blockIdx.y;               // j-tile (8 j's)
    int tid = threadIdx.x, wv = tid >> 6, lane = tid & 63;
    int quad = lane >> 4, l15 = lane & 15;
    int wm = wv & 1, wn = wv >> 1;

    const unsigned short* srcN = A2 + ((size_t)(bx * 128)) * 128;   // (i,c) rows
    const unsigned short* srcM0 = B2 + ((size_t)(by * 256)) * 128;  // (j,d) rows

    // ---- Stage A: two 128x128 K=128 passes ----
    #pragma unroll
    for (int pass = 0; pass < 2; ++pass) {
        const unsigned short* srcM = srcM0 + (size_t)pass * 128 * 128;
        f32x4 acc[4][4];
        #pragma unroll
        for (int a = 0; a < 4; ++a)
            #pragma unroll
            for (int b = 0; b < 4; ++b) acc[a][b] = (f32x4){0.f, 0.f, 0.f, 0.f};

        #pragma unroll
        for (int ks = 0; ks < 4; ++ks) {
            bf16x8 am[4], bn[4];
            #pragma unroll
            for (int mb = 0; mb < 4; ++mb)
                am[mb] = *(const bf16x8*)(srcM + (size_t)(wm * 64 + mb * 16 + l15) * 128 + ks * 32 + quad * 8);
            #pragma unroll
            for (int nb = 0; nb < 4; ++nb)
                bn[nb] = *(const bf16x8*)(srcN + (size_t)(wn * 64 + nb * 16 + l15) * 128 + ks * 32 + quad * 8);
            #pragma unroll
            for (int mb = 0; mb < 4; ++mb)
                #pragma unroll
                for (int nb = 0; nb < 4; ++nb)
                    acc[mb][nb] = __builtin_amdgcn_mfma_f32_16x16x32_bf16(am[mb], bn[nb], acc[mb][nb], 0, 0, 0);
        }

        // write o tile: D row m_=(jl,d), col n_=(il,c); regs = 4 consecutive d
        #pragma unroll
        for (int mb = 0; mb < 4; ++mb) {
            int m_ = wm * 64 + mb * 16 + quad * 4;
            int d0 = m_ & 31;
            int jl = pass * 4 + (m_ >> 5);
            #pragma unroll
            for (int nb = 0; nb < 4; ++nb) {
                int n_ = wn * 64 + nb * 16 + l15;
                int c = n_ & 31, il = n_ >> 5;
                int pair = il * 8 + jl;
                int e0 = c * 32 + d0;
                f32x4 a4 = acc[mb][nb];
                unsigned int p0 = (unsigned)f32_to_bf16(a4[0]) | ((unsigned)f32_to_bf16(a4[1]) << 16);
                unsigned int p1 = (unsigned)f32_to_bf16(a4[2]) | ((unsigned)f32_to_bf16(a4[3]) << 16);
                u32x2 pv = {p0, p1};
                int chunk = e0 >> 3;
                int phys = chunk ^ ((chunk >> 3) & 7) ^ (pair & 7);
                *(u32x2*)(olds + pair * 2048 + phys * 16 + (e0 & 7) * 2) = pv;
            }
        }
    }
    __syncthreads();

    // ---- Stage B: D[zo][pair], K=1024. Wave wv owns zo in [wv*32, wv*32+32).
    f32x4 acc2[2][2];
    #pragma unroll
    for (int a = 0; a < 2; ++a)
        #pragma unroll
        for (int b = 0; b < 2; ++b) acc2[a][b] = (f32x4){0.f, 0.f, 0.f, 0.f};

    #pragma unroll 4
    for (int kt = 0; kt < 32; ++kt) {
        bf16x8 af[2], bf2[2];
        #pragma unroll
        for (int zb = 0; zb < 2; ++zb)
            af[zb] = *(const bf16x8*)(wobf + (size_t)(wv * 32 + zb * 16 + l15) * 1024 + kt * 32 + quad * 8);
        #pragma unroll
        for (int pb = 0; pb < 2; ++pb) {
            int pair = pb * 16 + l15;
            int chunk = kt * 4 + quad;
            int phys = chunk ^ ((chunk >> 3) & 7) ^ (pair & 7);
            bf2[pb] = *(const bf16x8*)(olds + pair * 2048 + phys * 16);
        }
        #pragma unroll
        for (int zb = 0; zb < 2; ++zb)
            #pragma unroll
            for (int pb = 0; pb < 2; ++pb)
                acc2[zb][pb] = __builtin_amdgcn_mfma_f32_16x16x32_bf16(af[zb], bf2[pb], acc2[zb][pb], 0, 0, 0);
    }

    // epilogue: z = (acc + bo) / n_seq
    #pragma unroll
    for (int zb = 0; zb < 2; ++zb) {
        int zo = wv * 32 + zb * 16 + quad * 4;
        f32x4 b4 = *(const f32x4*)(bo + zo);
        #pragma unroll
        for (int pb = 0; pb < 2; ++pb) {
            int pair = pb * 16 + l15;
            int i = bx * 4 + (pair >> 3);
            int j = by * 8 + (pair & 7);
            f32x4 v;
            #pragma unroll
            for (int reg = 0; reg < 4; ++reg)
                v[reg] = (acc2[zb][pb][reg] + b4[reg]) * (1.0f / 128.0f);
            *(f32x4*)(out + ((size_t)(i * 256 + j)) * 128 + zo) = v;
        }
    }
}

extern "C" void kernel_launch(void* const* d_in, const int* in_sizes, int n_in,
                              void* d_out, int out_size, void* d_ws, size_t ws_size,
                              hipStream_t stream) {
    const float* m   = (const float*)d_in[0];
    const float* lnw = (const float*)d_in[1];
    const float* lnb = (const float*)d_in[2];
    const float* w1  = (const float*)d_in[3];
    const float* b1  = (const float*)d_in[4];
    const float* w2  = (const float*)d_in[5];
    const float* b2  = (const float*)d_in[6];
    const float* wo  = (const float*)d_in[7];
    const float* bo  = (const float*)d_in[8];
    float* out = (float*)d_out;
    char* ws = (char*)d_ws;

    unsigned short* Wbf  = (unsigned short*)(ws);                       // 32 KB
    unsigned short* wobf = (unsigned short*)(ws + 32768);               // 256 KB
    unsigned short* A2   = (unsigned short*)(ws + 32768 + 262144);      // 2 MB
    unsigned short* B2   = (unsigned short*)(ws + 32768 + 262144 + 2097152); // 2 MB

    hipLaunchKernelGGL(k_prep, dim3(512), dim3(256), 0, stream, w1, w2, wo, Wbf, wobf);
    hipLaunchKernelGGL(k_ln_proj, dim3(256), dim3(256), 0, stream,
                       m, lnw, lnb, b1, b2, Wbf, A2, B2);
    hipLaunchKernelGGL(k_fused, dim3(64, 32), dim3(256), 0, stream,
                       A2, B2, wobf, bo, out);
}

// Round 3
// 147.560 us; speedup vs baseline: 1.5675x; 1.5675x over previous
//
#include <hip/hip_runtime.h>
#include <hip/hip_bf16.h>
#include <stdint.h>

#define N_RES 256
#define CMDIM 256

typedef __attribute__((ext_vector_type(8))) short bf16x8;
typedef __attribute__((ext_vector_type(4))) float f32x4;
typedef __attribute__((ext_vector_type(2))) unsigned int u32x2;

__device__ __forceinline__ unsigned short f32_to_bf16(float f) {
    union { float f; unsigned int u; } v; v.f = f;
    unsigned int u = v.u;
    return (unsigned short)((u + 0x7FFFu + ((u >> 16) & 1u)) >> 16);
}

// Fragment-linear layouts (all bf16):
//   A2f/B2f: element(row, s)  -> ((row>>4)*4  + (s>>5))*512 + ((s>>3)&3)*128 + (row&15)*8 + (s&7)
//   Wbf:     element(ch, cm)  -> ((ch>>4)*8  + (cm>>5))*512 + ((cm>>3)&3)*128 + (ch&15)*8 + (cm&7)
//   wof:     element(zo, k)   -> ((zo>>4)*32 + (k>>5))*512 + ((k>>3)&3)*128 + (zo&15)*8 + (k&7)
// A wave reading (blk, ks) does one coalesced 1 KB load at base + lane*16B.

// ---------------- K0: convert + repack weights to bf16 frag-linear ----------------
__global__ __launch_bounds__(256) void k_prep(
    const float* __restrict__ w1, const float* __restrict__ w2,
    const float* __restrict__ wo,
    unsigned short* __restrict__ Wbf, unsigned short* __restrict__ wof)
{
    int t = blockIdx.x * 256 + threadIdx.x;
    if (t < 16384) {
        int ch = t >> 8, cm = t & 255;
        float v = (ch < 32) ? w1[ch * 256 + cm] : w2[(ch - 32) * 256 + cm];
        int addr = ((ch >> 4) * 8 + (cm >> 5)) * 512 + ((cm >> 3) & 3) * 128 + (ch & 15) * 8 + (cm & 7);
        Wbf[addr] = f32_to_bf16(v);
    }
    if (t < 131072) {
        int zo = t >> 10, k = t & 1023;
        int addr = ((zo >> 4) * 32 + (k >> 5)) * 512 + ((k >> 3) & 3) * 128 + (zo & 15) * 8 + (k & 7);
        wof[addr] = f32_to_bf16(wo[t]);
    }
}

// ---------------- K1: LayerNorm + dual projection ----------------
// 1024 WGs: b = i*4 + sblk. Each WG: LN for 32 rows (s in sblk*32..+32) of
// residue i, then D[64 ch][32 s] = W * mn^T, written frag-linear to A2f/B2f.
__global__ __launch_bounds__(256) void k_ln_proj(
    const float* __restrict__ m, const float* __restrict__ lnw, const float* __restrict__ lnb,
    const float* __restrict__ b1, const float* __restrict__ b2,
    const unsigned short* __restrict__ Wbf,
    unsigned short* __restrict__ A2f, unsigned short* __restrict__ B2f)
{
    __shared__ unsigned short mn[32 * 256];   // 16 KB; rows 512 B, 16B-chunk XOR swizzle
    int b = blockIdx.x;
    int i = b >> 2, sblk = b & 3;
    int tid = threadIdx.x;
    int wv = tid >> 6, lane = tid & 63;
    int quad = lane >> 4, l15 = lane & 15;

    f32x4 lw = *(const f32x4*)(lnw + lane * 4);
    f32x4 lb = *(const f32x4*)(lnb + lane * 4);

    #pragma unroll
    for (int r = 0; r < 8; ++r) {
        int sl = wv * 8 + r;
        int s = sblk * 32 + sl;
        const float* row = m + ((size_t)s * N_RES + i) * CMDIM;
        f32x4 x = *(const f32x4*)(row + lane * 4);
        float s1 = x[0] + x[1] + x[2] + x[3];
        float s2 = x[0]*x[0] + x[1]*x[1] + x[2]*x[2] + x[3]*x[3];
        #pragma unroll
        for (int off = 32; off; off >>= 1) {
            s1 += __shfl_xor(s1, off);
            s2 += __shfl_xor(s2, off);
        }
        float mu = s1 * (1.0f / 256.0f);
        float var = s2 * (1.0f / 256.0f) - mu * mu;
        float rstd = rsqrtf(var + 1e-5f);
        float n0 = (x[0] - mu) * rstd * lw[0] + lb[0];
        float n1 = (x[1] - mu) * rstd * lw[1] + lb[1];
        float n2 = (x[2] - mu) * rstd * lw[2] + lb[2];
        float n3 = (x[3] - mu) * rstd * lw[3] + lb[3];
        unsigned int p0 = (unsigned)f32_to_bf16(n0) | ((unsigned)f32_to_bf16(n1) << 16);
        unsigned int p1 = (unsigned)f32_to_bf16(n2) | ((unsigned)f32_to_bf16(n3) << 16);
        int chunk = lane >> 1;
        int pos = (chunk & 16) | ((chunk ^ sl) & 15);
        unsigned int* dst = (unsigned int*)((char*)mn + sl * 512 + pos * 16 + (lane & 1) * 8);
        dst[0] = p0; dst[1] = p1;
    }
    __syncthreads();

    // Preload all W fragments for this wave's ch-block (coalesced, L2-hot).
    bf16x8 af[8];
    #pragma unroll
    for (int ks = 0; ks < 8; ++ks)
        af[ks] = *(const bf16x8*)(Wbf + (wv * 8 + ks) * 512 + lane * 8);

    f32x4 acc[2];
    acc[0] = (f32x4){0.f, 0.f, 0.f, 0.f};
    acc[1] = (f32x4){0.f, 0.f, 0.f, 0.f};
    #pragma unroll
    for (int ks = 0; ks < 8; ++ks) {
        #pragma unroll
        for (int nb = 0; nb < 2; ++nb) {
            int sl = nb * 16 + l15;
            int chunk = ks * 4 + quad;
            int pos = (chunk & 16) | ((chunk ^ sl) & 15);
            bf16x8 bf = *(const bf16x8*)((char*)mn + sl * 512 + pos * 16);
            acc[nb] = __builtin_amdgcn_mfma_f32_16x16x32_bf16(af[ks], bf, acc[nb], 0, 0, 0);
        }
    }

    // Epilogue: D row ch = wv*16 + quad*4 + reg, col s = sblk*32 + nb*16 + l15.
    const float* bsrc = (wv < 2) ? b1 : b2;
    f32x4 bias = *(const f32x4*)(bsrc + (wv & 1) * 16 + quad * 4);
    unsigned short* dst = (wv < 2) ? A2f : B2f;
    #pragma unroll
    for (int nb = 0; nb < 2; ++nb) {
        int s = sblk * 32 + nb * 16 + l15;
        int shi = ((s >> 3) & 3) * 128 + (s & 7);
        #pragma unroll
        for (int reg = 0; reg < 4; ++reg) {
            int ic = i * 32 + (wv & 1) * 16 + quad * 4 + reg;
            int addr = ((ic >> 4) * 4 + sblk) * 512 + shi + (ic & 15) * 8;
            dst[addr] = f32_to_bf16(acc[nb][reg] + bias[reg]);
        }
    }
}

// ---------------- K2: fused GEMM1+GEMM2 ----------------
// WG = 4 i x 8 j = 32 pairs. Stage A: o tile (32x1024 bf16) -> swizzled LDS,
// fragments loaded coalesced (frag-linear) from L2. Stage B: z = wo . o^T,
// K=1024, wo fragments coalesced from L2, 2-deep software pipeline.
__global__ __launch_bounds__(256, 2) void k_fused(
    const unsigned short* __restrict__ A2f, const unsigned short* __restrict__ B2f,
    const unsigned short* __restrict__ wof, const float* __restrict__ bo,
    float* __restrict__ out)
{
    __shared__ char olds[32 * 2048];   // 64 KB
    int bx = blockIdx.x;               // 4 i's
    int by = blockIdx.y;               // 8 j's
    int tid = threadIdx.x, wv = tid >> 6, lane = tid & 63;
    int quad = lane >> 4, l15 = lane & 15;
    int wm = wv & 1, wn = wv >> 1;

    // ---- Stage A ----
    // bn (A2f cols, n-side) reused across both passes: preload 16 frags.
    bf16x8 bn[4][4];
    #pragma unroll
    for (int ks = 0; ks < 4; ++ks)
        #pragma unroll
        for (int nb = 0; nb < 4; ++nb)
            bn[ks][nb] = *(const bf16x8*)(A2f + (size_t)(((bx * 8 + wn * 4 + nb) * 4 + ks) * 512) + lane * 8);

    for (int pass = 0; pass < 2; ++pass) {
        f32x4 acc[4][4];
        #pragma unroll
        for (int a = 0; a < 4; ++a)
            #pragma unroll
            for (int b = 0; b < 4; ++b) acc[a][b] = (f32x4){0.f, 0.f, 0.f, 0.f};

        #pragma unroll
        for (int ks = 0; ks < 4; ++ks) {
            bf16x8 am[4];
            #pragma unroll
            for (int mb = 0; mb < 4; ++mb)
                am[mb] = *(const bf16x8*)(B2f + (size_t)(((by * 16 + pass * 8 + wm * 4 + mb) * 4 + ks) * 512) + lane * 8);
            #pragma unroll
            for (int mb = 0; mb < 4; ++mb)
                #pragma unroll
                for (int nb = 0; nb < 4; ++nb)
                    acc[mb][nb] = __builtin_amdgcn_mfma_f32_16x16x32_bf16(am[mb], bn[ks][nb], acc[mb][nb], 0, 0, 0);
        }

        // write o tile to LDS: row m_=(jl,d), col n_=(il,c)
        #pragma unroll
        for (int mb = 0; mb < 4; ++mb) {
            int m_ = wm * 64 + mb * 16 + quad * 4;
            int d0 = m_ & 31;
            int jl = pass * 4 + (m_ >> 5);
            #pragma unroll
            for (int nb = 0; nb < 4; ++nb) {
                int n_ = wn * 64 + nb * 16 + l15;
                int c = n_ & 31, il = n_ >> 5;
                int pair = il * 8 + jl;
                int e0 = c * 32 + d0;
                f32x4 a4 = acc[mb][nb];
                unsigned int p0 = (unsigned)f32_to_bf16(a4[0]) | ((unsigned)f32_to_bf16(a4[1]) << 16);
                unsigned int p1 = (unsigned)f32_to_bf16(a4[2]) | ((unsigned)f32_to_bf16(a4[3]) << 16);
                u32x2 pv = {p0, p1};
                int chunk = e0 >> 3;
                int phys = chunk ^ ((chunk >> 3) & 7) ^ (pair & 7);
                *(u32x2*)(olds + pair * 2048 + phys * 16 + (e0 & 7) * 2) = pv;
            }
        }
    }
    __syncthreads();

    // ---- Stage B: D[zo 32][pair 32] per wave, K=1024, 2-deep pipeline ----
    f32x4 acc2[2][2];
    #pragma unroll
    for (int a = 0; a < 2; ++a)
        #pragma unroll
        for (int b = 0; b < 2; ++b) acc2[a][b] = (f32x4){0.f, 0.f, 0.f, 0.f};

    const unsigned short* wbase = wof + (size_t)(wv * 2 * 32) * 512 + lane * 8;

    bf16x8 afA[2], bfA[2], afB[2], bfB[2];
    #pragma unroll
    for (int zb = 0; zb < 2; ++zb)
        afA[zb] = *(const bf16x8*)(wbase + (size_t)(zb * 32) * 512);
    #pragma unroll
    for (int pb = 0; pb < 2; ++pb) {
        int pair = pb * 16 + l15;
        int chunk = quad;
        int phys = chunk ^ ((chunk >> 3) & 7) ^ (pair & 7);
        bfA[pb] = *(const bf16x8*)(olds + pair * 2048 + phys * 16);
    }

    #pragma unroll 2
    for (int kt = 0; kt < 32; kt += 2) {
        // prefetch kt+1
        #pragma unroll
        for (int zb = 0; zb < 2; ++zb)
            afB[zb] = *(const bf16x8*)(wbase + (size_t)(zb * 32 + kt + 1) * 512);
        #pragma unroll
        for (int pb = 0; pb < 2; ++pb) {
            int pair = pb * 16 + l15;
            int chunk = (kt + 1) * 4 + quad;
            int phys = chunk ^ ((chunk >> 3) & 7) ^ (pair & 7);
            bfB[pb] = *(const bf16x8*)(olds + pair * 2048 + phys * 16);
        }
        #pragma unroll
        for (int zb = 0; zb < 2; ++zb)
            #pragma unroll
            for (int pb = 0; pb < 2; ++pb)
                acc2[zb][pb] = __builtin_amdgcn_mfma_f32_16x16x32_bf16(afA[zb], bfA[pb], acc2[zb][pb], 0, 0, 0);
        // prefetch kt+2
        if (kt + 2 < 32) {
            #pragma unroll
            for (int zb = 0; zb < 2; ++zb)
                afA[zb] = *(const bf16x8*)(wbase + (size_t)(zb * 32 + kt + 2) * 512);
            #pragma unroll
            for (int pb = 0; pb < 2; ++pb) {
                int pair = pb * 16 + l15;
                int chunk = (kt + 2) * 4 + quad;
                int phys = chunk ^ ((chunk >> 3) & 7) ^ (pair & 7);
                bfA[pb] = *(const bf16x8*)(olds + pair * 2048 + phys * 16);
            }
        }
        #pragma unroll
        for (int zb = 0; zb < 2; ++zb)
            #pragma unroll
            for (int pb = 0; pb < 2; ++pb)
                acc2[zb][pb] = __builtin_amdgcn_mfma_f32_16x16x32_bf16(afB[zb], bfB[pb], acc2[zb][pb], 0, 0, 0);
    }

    // epilogue: z = (acc + bo) / n_seq
    #pragma unroll
    for (int zb = 0; zb < 2; ++zb) {
        int zo = wv * 32 + zb * 16 + quad * 4;
        f32x4 b4 = *(const f32x4*)(bo + zo);
        #pragma unroll
        for (int pb = 0; pb < 2; ++pb) {
            int pair = pb * 16 + l15;
            int i = bx * 4 + (pair >> 3);
            int j = by * 8 + (pair & 7);
            f32x4 v;
            #pragma unroll
            for (int reg = 0; reg < 4; ++reg)
                v[reg] = (acc2[zb][pb][reg] + b4[reg]) * (1.0f / 128.0f);
            *(f32x4*)(out + ((size_t)(i * 256 + j)) * 128 + zo) = v;
        }
    }
}

extern "C" void kernel_launch(void* const* d_in, const int* in_sizes, int n_in,
                              void* d_out, int out_size, void* d_ws, size_t ws_size,
                              hipStream_t stream) {
    const float* m   = (const float*)d_in[0];
    const float* lnw = (const float*)d_in[1];
    const float* lnb = (const float*)d_in[2];
    const float* w1  = (const float*)d_in[3];
    const float* b1  = (const float*)d_in[4];
    const float* w2  = (const float*)d_in[5];
    const float* b2  = (const float*)d_in[6];
    const float* wo  = (const float*)d_in[7];
    const float* bo  = (const float*)d_in[8];
    float* out = (float*)d_out;
    char* ws = (char*)d_ws;

    unsigned short* Wbf = (unsigned short*)(ws);                            // 32 KB
    unsigned short* wof = (unsigned short*)(ws + 32768);                    // 256 KB
    unsigned short* A2f = (unsigned short*)(ws + 32768 + 262144);           // 2 MB
    unsigned short* B2f = (unsigned short*)(ws + 32768 + 262144 + 2097152); // 2 MB

    hipLaunchKernelGGL(k_prep, dim3(512), dim3(256), 0, stream, w1, w2, wo, Wbf, wof);
    hipLaunchKernelGGL(k_ln_proj, dim3(1024), dim3(256), 0, stream,
                       m, lnw, lnb, b1, b2, Wbf, A2f, B2f);
    hipLaunchKernelGGL(k_fused, dim3(64, 32), dim3(256), 0, stream,
                       A2f, B2f, wof, bo, out);
}

// Round 4
// 139.231 us; speedup vs baseline: 1.6613x; 1.0598x over previous
//
#include <hip/hip_runtime.h>
#include <hip/hip_bf16.h>
#include <stdint.h>

#define N_RES 256
#define CMDIM 256

typedef __attribute__((ext_vector_type(8))) short bf16x8;
typedef __attribute__((ext_vector_type(4))) float f32x4;
typedef __attribute__((ext_vector_type(2))) unsigned int u32x2;

__device__ __forceinline__ unsigned short f32_to_bf16(float f) {
    union { float f; unsigned int u; } v; v.f = f;
    unsigned int u = v.u;
    return (unsigned short)((u + 0x7FFFu + ((u >> 16) & 1u)) >> 16);
}

// Fragment-linear layouts (all bf16):
//   A2f/B2f: element(row, s)  -> ((row>>4)*4  + (s>>5))*512 + ((s>>3)&3)*128 + (row&15)*8 + (s&7)
//   Wbf:     element(ch, cm)  -> ((ch>>4)*8  + (cm>>5))*512 + ((cm>>3)&3)*128 + (ch&15)*8 + (cm&7)
//   wof:     element(zo, k)   -> ((zo>>4)*32 + (k>>5))*512 + ((k>>3)&3)*128 + (zo&15)*8 + (k&7)
// A wave reading (blk, ks) does one coalesced 1 KB load at base + lane*16B.

// ---------------- K0: convert + repack weights ----------------
__global__ __launch_bounds__(256) void k_prep(
    const float* __restrict__ w1, const float* __restrict__ w2,
    const float* __restrict__ wo,
    unsigned short* __restrict__ Wbf, unsigned short* __restrict__ wof)
{
    int t = blockIdx.x * 256 + threadIdx.x;
    if (t < 16384) {
        int ch = t >> 8, cm = t & 255;
        float v = (ch < 32) ? w1[ch * 256 + cm] : w2[(ch - 32) * 256 + cm];
        int addr = ((ch >> 4) * 8 + (cm >> 5)) * 512 + ((cm >> 3) & 3) * 128 + (ch & 15) * 8 + (cm & 7);
        Wbf[addr] = f32_to_bf16(v);
    }
    if (t < 131072) {
        int zo = t >> 10, k = t & 1023;
        int addr = ((zo >> 4) * 32 + (k >> 5)) * 512 + ((k >> 3) & 3) * 128 + (zo & 15) * 8 + (k & 7);
        wof[addr] = f32_to_bf16(wo[t]);
    }
}

// ---------------- K1: LayerNorm + dual projection ----------------
// 1024 WGs: b = i*4 + sblk. LN 32 rows, MFMA D[64ch][32s] = W*mn^T,
// epilogue staged through LDS -> coalesced dwordx4 global stores.
__global__ __launch_bounds__(256) void k_ln_proj(
    const float* __restrict__ m, const float* __restrict__ lnw, const float* __restrict__ lnb,
    const float* __restrict__ b1, const float* __restrict__ b2,
    const unsigned short* __restrict__ Wbf,
    unsigned short* __restrict__ A2f, unsigned short* __restrict__ B2f)
{
    __shared__ unsigned short mn[32 * 256];   // 16 KB
    __shared__ unsigned short stg[2048];      // 4 KB epilogue staging
    int b = blockIdx.x;
    int i = b >> 2, sblk = b & 3;
    int tid = threadIdx.x;
    int wv = tid >> 6, lane = tid & 63;
    int quad = lane >> 4, l15 = lane & 15;

    f32x4 lw = *(const f32x4*)(lnw + lane * 4);
    f32x4 lb = *(const f32x4*)(lnb + lane * 4);

    #pragma unroll
    for (int r = 0; r < 8; ++r) {
        int sl = wv * 8 + r;
        int s = sblk * 32 + sl;
        const float* row = m + ((size_t)s * N_RES + i) * CMDIM;
        f32x4 x = *(const f32x4*)(row + lane * 4);
        float s1 = x[0] + x[1] + x[2] + x[3];
        float s2 = x[0]*x[0] + x[1]*x[1] + x[2]*x[2] + x[3]*x[3];
        #pragma unroll
        for (int off = 32; off; off >>= 1) {
            s1 += __shfl_xor(s1, off);
            s2 += __shfl_xor(s2, off);
        }
        float mu = s1 * (1.0f / 256.0f);
        float var = s2 * (1.0f / 256.0f) - mu * mu;
        float rstd = rsqrtf(var + 1e-5f);
        float n0 = (x[0] - mu) * rstd * lw[0] + lb[0];
        float n1 = (x[1] - mu) * rstd * lw[1] + lb[1];
        float n2 = (x[2] - mu) * rstd * lw[2] + lb[2];
        float n3 = (x[3] - mu) * rstd * lw[3] + lb[3];
        unsigned int p0 = (unsigned)f32_to_bf16(n0) | ((unsigned)f32_to_bf16(n1) << 16);
        unsigned int p1 = (unsigned)f32_to_bf16(n2) | ((unsigned)f32_to_bf16(n3) << 16);
        int chunk = lane >> 1;
        int pos = (chunk & 16) | ((chunk ^ sl) & 15);
        unsigned int* dst = (unsigned int*)((char*)mn + sl * 512 + pos * 16 + (lane & 1) * 8);
        dst[0] = p0; dst[1] = p1;
    }
    __syncthreads();

    bf16x8 af[8];
    #pragma unroll
    for (int ks = 0; ks < 8; ++ks)
        af[ks] = *(const bf16x8*)(Wbf + (wv * 8 + ks) * 512 + lane * 8);

    f32x4 acc[2];
    acc[0] = (f32x4){0.f, 0.f, 0.f, 0.f};
    acc[1] = (f32x4){0.f, 0.f, 0.f, 0.f};
    #pragma unroll
    for (int ks = 0; ks < 8; ++ks) {
        #pragma unroll
        for (int nb = 0; nb < 2; ++nb) {
            int sl = nb * 16 + l15;
            int chunk = ks * 4 + quad;
            int pos = (chunk & 16) | ((chunk ^ sl) & 15);
            bf16x8 bf = *(const bf16x8*)((char*)mn + sl * 512 + pos * 16);
            acc[nb] = __builtin_amdgcn_mfma_f32_16x16x32_bf16(af[ks], bf, acc[nb], 0, 0, 0);
        }
    }

    // Epilogue: quantize into stg in store-linear (frag-linear) order.
    // stg offset = (wv>>1)*1024 + (wv&1)*512 + ((sl>>3)&3)*128 + (quad*4+reg)*8 + (sl&7)
    const float* bsrc = (wv < 2) ? b1 : b2;
    f32x4 bias = *(const f32x4*)(bsrc + (wv & 1) * 16 + quad * 4);
    unsigned short* sbase = stg + (wv >> 1) * 1024 + (wv & 1) * 512 + quad * 32;
    #pragma unroll
    for (int nb = 0; nb < 2; ++nb) {
        int sl = nb * 16 + l15;
        int soff = ((sl >> 3) & 3) * 128 + (sl & 7);
        #pragma unroll
        for (int reg = 0; reg < 4; ++reg)
            sbase[soff + reg * 8] = f32_to_bf16(acc[nb][reg] + bias[reg]);
    }
    __syncthreads();

    // Coalesced write-out: thread t -> 16B at stg[t*8], global chunk (part,blk).
    int part = tid >> 7, blk = (tid >> 6) & 1, l = tid & 63;
    unsigned short* gdst = (part ? B2f : A2f) + ((i * 2 + blk) * 4 + sblk) * 512 + l * 8;
    *(bf16x8*)gdst = *(const bf16x8*)(stg + tid * 8);
}

// ---------------- K2: fused GEMM1+GEMM2 ----------------
// o LDS layout: byte addr = chunk*512 + (pair ^ (chunk&31))*16 + (e&7)*2,
// chunk = e>>3, e = c*32+d in [0,1024), pair in [0,32).
__global__ __launch_bounds__(256, 2) void k_fused(
    const unsigned short* __restrict__ A2f, const unsigned short* __restrict__ B2f,
    const unsigned short* __restrict__ wof, const float* __restrict__ bo,
    float* __restrict__ out)
{
    __shared__ char olds[65536];
    int bx = blockIdx.x;               // 4 i's
    int by = blockIdx.y;               // 8 j's
    int tid = threadIdx.x, wv = tid >> 6, lane = tid & 63;
    int quad = lane >> 4, l15 = lane & 15;
    int wm = wv & 1, wn = wv >> 1;

    // ---- Stage A ----
    bf16x8 bn[4][4];
    #pragma unroll
    for (int ks = 0; ks < 4; ++ks)
        #pragma unroll
        for (int nb = 0; nb < 4; ++nb)
            bn[ks][nb] = *(const bf16x8*)(A2f + (size_t)(((bx * 8 + wn * 4 + nb) * 4 + ks) * 512) + lane * 8);

    #pragma unroll
    for (int pass = 0; pass < 2; ++pass) {
        f32x4 acc[4][4];
        #pragma unroll
        for (int a = 0; a < 4; ++a)
            #pragma unroll
            for (int b = 0; b < 4; ++b) acc[a][b] = (f32x4){0.f, 0.f, 0.f, 0.f};

        bf16x8 amC[4], amN[4];
        #pragma unroll
        for (int mb = 0; mb < 4; ++mb)
            amC[mb] = *(const bf16x8*)(B2f + (size_t)(((by * 16 + pass * 8 + wm * 4 + mb) * 4 + 0) * 512) + lane * 8);

        #pragma unroll
        for (int ks = 0; ks < 4; ++ks) {
            if (ks < 3) {
                #pragma unroll
                for (int mb = 0; mb < 4; ++mb)
                    amN[mb] = *(const bf16x8*)(B2f + (size_t)(((by * 16 + pass * 8 + wm * 4 + mb) * 4 + ks + 1) * 512) + lane * 8);
            }
            #pragma unroll
            for (int mb = 0; mb < 4; ++mb)
                #pragma unroll
                for (int nb = 0; nb < 4; ++nb)
                    acc[mb][nb] = __builtin_amdgcn_mfma_f32_16x16x32_bf16(amC[mb], bn[ks][nb], acc[mb][nb], 0, 0, 0);
            #pragma unroll
            for (int mb = 0; mb < 4; ++mb) amC[mb] = amN[mb];
        }

        // write o tile: row m_=(jl,d), col n_=(il,c)
        #pragma unroll
        for (int mb = 0; mb < 4; ++mb) {
            int m_ = wm * 64 + mb * 16 + quad * 4;
            int d0 = m_ & 31;
            int jl = pass * 4 + (m_ >> 5);
            #pragma unroll
            for (int nb = 0; nb < 4; ++nb) {
                int n_ = wn * 64 + nb * 16 + l15;
                int c = n_ & 31, il = n_ >> 5;
                int pair = il * 8 + jl;
                int e0 = c * 32 + d0;
                int chunk = e0 >> 3;
                int phys = pair ^ (chunk & 31);
                f32x4 a4 = acc[mb][nb];
                unsigned int p0 = (unsigned)f32_to_bf16(a4[0]) | ((unsigned)f32_to_bf16(a4[1]) << 16);
                unsigned int p1 = (unsigned)f32_to_bf16(a4[2]) | ((unsigned)f32_to_bf16(a4[3]) << 16);
                u32x2 pv = {p0, p1};
                *(u32x2*)(olds + chunk * 512 + phys * 16 + (e0 & 7) * 2) = pv;
            }
        }
    }
    __syncthreads();

    // ---- Stage B: D[zo 32][pair 32] per wave, K=1024, 4-deep ring pipeline ----
    f32x4 acc2[2][2];
    #pragma unroll
    for (int a = 0; a < 2; ++a)
        #pragma unroll
        for (int b = 0; b < 2; ++b) acc2[a][b] = (f32x4){0.f, 0.f, 0.f, 0.f};

    const unsigned short* wbase = wof + (size_t)(wv * 2 * 32) * 512 + lane * 8;

    bf16x8 af[4][2], bfr[4][2];
    #pragma unroll
    for (int p = 0; p < 3; ++p) {
        #pragma unroll
        for (int zb = 0; zb < 2; ++zb)
            af[p][zb] = *(const bf16x8*)(wbase + (size_t)(zb * 32 + p) * 512);
        #pragma unroll
        for (int pb = 0; pb < 2; ++pb) {
            int pair = pb * 16 + l15;
            int chunk = p * 4 + quad;
            int phys = pair ^ (chunk & 31);
            bfr[p][pb] = *(const bf16x8*)(olds + chunk * 512 + phys * 16);
        }
    }

    #pragma unroll
    for (int kt = 0; kt < 32; ++kt) {
        int slot = kt & 3;
        if (kt + 3 < 32) {
            int pf = kt + 3, ps = pf & 3;
            #pragma unroll
            for (int zb = 0; zb < 2; ++zb)
                af[ps][zb] = *(const bf16x8*)(wbase + (size_t)(zb * 32 + pf) * 512);
            #pragma unroll
            for (int pb = 0; pb < 2; ++pb) {
                int pair = pb * 16 + l15;
                int chunk = pf * 4 + quad;
                int phys = pair ^ (chunk & 31);
                bfr[ps][pb] = *(const bf16x8*)(olds + chunk * 512 + phys * 16);
            }
        }
        #pragma unroll
        for (int zb = 0; zb < 2; ++zb)
            #pragma unroll
            for (int pb = 0; pb < 2; ++pb)
                acc2[zb][pb] = __builtin_amdgcn_mfma_f32_16x16x32_bf16(af[slot][zb], bfr[slot][pb], acc2[zb][pb], 0, 0, 0);
    }

    // epilogue: z = (acc + bo) / n_seq
    #pragma unroll
    for (int zb = 0; zb < 2; ++zb) {
        int zo = wv * 32 + zb * 16 + quad * 4;
        f32x4 b4 = *(const f32x4*)(bo + zo);
        #pragma unroll
        for (int pb = 0; pb < 2; ++pb) {
            int pair = pb * 16 + l15;
            int i = bx * 4 + (pair >> 3);
            int j = by * 8 + (pair & 7);
            f32x4 v;
            #pragma unroll
            for (int reg = 0; reg < 4; ++reg)
                v[reg] = (acc2[zb][pb][reg] + b4[reg]) * (1.0f / 128.0f);
            *(f32x4*)(out + ((size_t)(i * 256 + j)) * 128 + zo) = v;
        }
    }
}

extern "C" void kernel_launch(void* const* d_in, const int* in_sizes, int n_in,
                              void* d_out, int out_size, void* d_ws, size_t ws_size,
                              hipStream_t stream) {
    const float* m   = (const float*)d_in[0];
    const float* lnw = (const float*)d_in[1];
    const float* lnb = (const float*)d_in[2];
    const float* w1  = (const float*)d_in[3];
    const float* b1  = (const float*)d_in[4];
    const float* w2  = (const float*)d_in[5];
    const float* b2  = (const float*)d_in[6];
    const float* wo  = (const float*)d_in[7];
    const float* bo  = (const float*)d_in[8];
    float* out = (float*)d_out;
    char* ws = (char*)d_ws;

    unsigned short* Wbf = (unsigned short*)(ws);                            // 32 KB
    unsigned short* wof = (unsigned short*)(ws + 32768);                    // 256 KB
    unsigned short* A2f = (unsigned short*)(ws + 32768 + 262144);           // 2 MB
    unsigned short* B2f = (unsigned short*)(ws + 32768 + 262144 + 2097152); // 2 MB

    hipLaunchKernelGGL(k_prep, dim3(512), dim3(256), 0, stream, w1, w2, wo, Wbf, wof);
    hipLaunchKernelGGL(k_ln_proj, dim3(1024), dim3(256), 0, stream,
                       m, lnw, lnb, b1, b2, Wbf, A2f, B2f);
    hipLaunchKernelGGL(k_fused, dim3(64, 32), dim3(256), 0, stream,
                       A2f, B2f, wof, bo, out);
}